// Round 1
// baseline (587.968 us; speedup 1.0000x reference)
//
#include <hip/hip_runtime.h>
#include <math.h>

#define HH 2048
#define WW 2048
#define NPIX (HH*WW)
#define MAXNC 100

// stats layout (floats; key regions reinterpreted as uint32)
#define S_AREA 0
#define S_SX   100
#define S_SY   200
#define S_SHOT 300
#define S_MUX  400
#define S_MUY  500
#define S_CXX  600
#define S_CXY  700
#define S_CYY  800
#define S_RC   900
#define S_RS   1000
#define S_MG   1100
#define S_KMINX 1200
#define S_KMAXX 1300
#define S_KMINY 1400
#define S_KMAXY 1500
#define S_TOT  1600

__device__ __forceinline__ unsigned int encf(float f){
  unsigned int u = __float_as_uint(f);
  return (u & 0x80000000u) ? ~u : (u | 0x80000000u);
}
__device__ __forceinline__ float decf(unsigned int k){
  return (k & 0x80000000u) ? __uint_as_float(k & 0x7fffffffu) : __uint_as_float(~k);
}

__device__ __forceinline__ float blockReduceSum(float v, float* sh){
  int t = threadIdx.x;
  __syncthreads();
  sh[t] = v; __syncthreads();
  for (int o = 128; o > 0; o >>= 1){ if (t < o) sh[t] += sh[t+o]; __syncthreads(); }
  float r = sh[0]; __syncthreads();
  return r;
}
__device__ __forceinline__ float blockReduceMin(float v, float* sh){
  int t = threadIdx.x;
  __syncthreads();
  sh[t] = v; __syncthreads();
  for (int o = 128; o > 0; o >>= 1){ if (t < o) sh[t] = fminf(sh[t], sh[t+o]); __syncthreads(); }
  float r = sh[0]; __syncthreads();
  return r;
}
__device__ __forceinline__ float blockReduceMax(float v, float* sh){
  int t = threadIdx.x;
  __syncthreads();
  sh[t] = v; __syncthreads();
  for (int o = 128; o > 0; o >>= 1){ if (t < o) sh[t] = fmaxf(sh[t], sh[t+o]); __syncthreads(); }
  float r = sh[0]; __syncthreads();
  return r;
}

// ---------------- CCL ----------------

__global__ void k_init(const float* __restrict__ hot, int* __restrict__ lab, int* __restrict__ lut){
  int i = blockIdx.x*256 + threadIdx.x;
  if (i < NPIX) lab[i] = (hot[i] > 0.3f) ? (i + 1) : 0;
  if (i <= NPIX) lut[i] = i;
}

__global__ void k_scatter(const int* __restrict__ lab, int* __restrict__ lut){
  int p = blockIdx.x*256 + threadIdx.x;
  if (p >= NPIX) return;
  int l = lab[p];
  if (l == 0) return;                 // idx=0 contributions are reset by lut[0]=0 in ref
  int x = p & (WW-1);
  int y = p >> 11;
  int ylo = (y > 0) ? y-1 : y, yhi = (y < HH-1) ? y+1 : y;
  int xlo = (x > 0) ? x-1 : x, xhi = (x < WW-1) ? x+1 : x;
  int m = l;                          // window includes center; 0-pad never exceeds labels >= 0
  for (int yy = ylo; yy <= yhi; ++yy){
    int rb = yy << 11;
    for (int xx = xlo; xx <= xhi; ++xx) m = max(m, lab[rb + xx]);
  }
  if (m > l) atomicMax(&lut[l], m);
}

__global__ void k_compress(const int* __restrict__ src, int* __restrict__ dst){
  int i = blockIdx.x*256 + threadIdx.x;
  if (i > NPIX) return;
  int a = src[i];
  dst[i] = src[a];
}

__global__ void k_apply(int* __restrict__ lab, const int* __restrict__ lut){
  int p = blockIdx.x*256 + threadIdx.x;
  if (p >= NPIX) return;
  lab[p] = lut[lab[p]];
}

// ---------------- rank relabel ----------------

__global__ void k_clear(int* __restrict__ pres){
  int i = blockIdx.x*256 + threadIdx.x;
  if (i <= NPIX) pres[i] = 0;
}

__global__ void k_mark(const int* __restrict__ lab, int* __restrict__ pres){
  int p = blockIdx.x*256 + threadIdx.x;
  if (p < NPIX) pres[lab[p]] = 1;
}

__global__ void k_scan1(const int* __restrict__ pres, int* __restrict__ bsum){
  __shared__ int sh[256];
  int t = threadIdx.x;
  int base = blockIdx.x*4096 + t*16;
  int run = 0;
  #pragma unroll
  for (int k = 0; k < 16; ++k){ int idx = base + k; if (idx <= NPIX) run += pres[idx]; }
  sh[t] = run; __syncthreads();
  for (int o = 128; o > 0; o >>= 1){ if (t < o) sh[t] += sh[t+o]; __syncthreads(); }
  if (t == 0) bsum[blockIdx.x] = sh[0];
}

__global__ void k_scan2(int* __restrict__ bs, int nb){
  __shared__ int sh[1024];
  int t = threadIdx.x;
  int v = (t < nb) ? bs[t] : 0;
  sh[t] = v; __syncthreads();
  for (int o = 1; o < 1024; o <<= 1){
    int add = (t >= o) ? sh[t-o] : 0;
    __syncthreads();
    sh[t] += add;
    __syncthreads();
  }
  if (t < nb) bs[t] = (t == 0) ? 0 : sh[t-1];   // exclusive
  if (t == 1023 && nb > 1024) bs[1024] = sh[1023]; // nb <= 1025 in this problem
}

__global__ void k_scan3(int* __restrict__ pres, const int* __restrict__ bsum){
  __shared__ int sh[256];
  int t = threadIdx.x;
  int base = blockIdx.x*4096 + t*16;
  int v[16];
  int run = 0;
  #pragma unroll
  for (int k = 0; k < 16; ++k){
    int idx = base + k;
    int x = (idx <= NPIX) ? pres[idx] : 0;
    run += x; v[k] = run;
  }
  sh[t] = run; __syncthreads();
  for (int o = 1; o < 256; o <<= 1){
    int add = (t >= o) ? sh[t-o] : 0;
    __syncthreads();
    sh[t] += add;
    __syncthreads();
  }
  int thrExcl = sh[t] - run;
  int offs = bsum[blockIdx.x] + thrExcl;
  #pragma unroll
  for (int k = 0; k < 16; ++k){
    int idx = base + k;
    if (idx <= NPIX) pres[idx] = v[k] + offs - 1;   // rank = inclusive cumsum - 1
  }
}

__global__ void k_seg(int* __restrict__ lab, const int* __restrict__ ranks){
  int p = blockIdx.x*256 + threadIdx.x;
  if (p >= NPIX) return;
  int r = ranks[lab[p]];
  lab[p] = (r >= MAXNC) ? 0 : r;
}

// ---------------- per-segment stats ----------------

__global__ void k_clearstats(float* __restrict__ st){
  int i = blockIdx.x*256 + threadIdx.x;
  if (i < S_TOT) st[i] = (i >= S_KMINX) ? -0.0f : 0.0f;  // -0.0f bits == encf(0.0f)
}

__global__ void k_stats1(const int* __restrict__ lab, const float* __restrict__ hot, float* __restrict__ st){
  __shared__ float sh[256];
  float a0 = 0.f, x0 = 0.f, y0 = 0.f, h0 = 0.f;
  int stride = gridDim.x * blockDim.x;
  for (int p = blockIdx.x*blockDim.x + threadIdx.x; p < NPIX; p += stride){
    int s = lab[p];
    float xf = (float)(p & (WW-1));
    float yf = (float)(p >> 11);
    float hv = hot[p];
    if (s == 0){ a0 += 1.f; x0 += xf; y0 += yf; h0 += hv; }
    else {
      atomicAdd(&st[S_AREA+s], 1.f);
      atomicAdd(&st[S_SX+s], xf);
      atomicAdd(&st[S_SY+s], yf);
      atomicAdd(&st[S_SHOT+s], hv);
    }
  }
  a0 = blockReduceSum(a0, sh);
  x0 = blockReduceSum(x0, sh);
  y0 = blockReduceSum(y0, sh);
  h0 = blockReduceSum(h0, sh);
  if (threadIdx.x == 0){
    atomicAdd(&st[S_AREA], a0);
    atomicAdd(&st[S_SX], x0);
    atomicAdd(&st[S_SY], y0);
    atomicAdd(&st[S_SHOT], h0);
  }
}

__global__ void k_mu(float* __restrict__ st){
  int s = threadIdx.x;
  if (s < MAXNC){
    float a = st[S_AREA+s];
    st[S_MUX+s] = st[S_SX+s] / a;   // 0/0 -> NaN matches ref
    st[S_MUY+s] = st[S_SY+s] / a;
  }
}

__global__ void k_stats2(const int* __restrict__ lab, float* __restrict__ st){
  __shared__ float sh[256];
  float xx0 = 0.f, xy0 = 0.f, yy0 = 0.f;
  int stride = gridDim.x * blockDim.x;
  for (int p = blockIdx.x*blockDim.x + threadIdx.x; p < NPIX; p += stride){
    int s = lab[p];
    float cx = (float)(p & (WW-1)) - st[S_MUX+s];
    float cy = (float)(p >> 11)    - st[S_MUY+s];
    float pxx = cx*cx, pxy = cx*cy, pyy = cy*cy;
    if (s == 0){ xx0 += pxx; xy0 += pxy; yy0 += pyy; }
    else {
      atomicAdd(&st[S_CXX+s], pxx);
      atomicAdd(&st[S_CXY+s], pxy);
      atomicAdd(&st[S_CYY+s], pyy);
    }
  }
  xx0 = blockReduceSum(xx0, sh);
  xy0 = blockReduceSum(xy0, sh);
  yy0 = blockReduceSum(yy0, sh);
  if (threadIdx.x == 0){
    atomicAdd(&st[S_CXX], xx0);
    atomicAdd(&st[S_CXY], xy0);
    atomicAdd(&st[S_CYY], yy0);
  }
}

__global__ void k_svd(float* __restrict__ st){
  int s = threadIdx.x;
  if (s >= MAXNC) return;
  float a = st[S_AREA+s];
  float vx  = st[S_CXX+s] / a;
  float vxy = st[S_CXY+s] / a;
  float vy  = st[S_CYY+s] / a;
  float theta = 0.5f * atan2f(2.0f*vxy, vx - vy);
  float c = cosf(theta), sn = sinf(theta);
  float tr = vx + vy;
  float d = (vx - vy)*(vx - vy) + 4.0f*vxy*vxy;
  float disc = fmaxf(d, 1e-12f);
  float sq = sqrtf(disc);
  float l2 = fmaxf((tr - sq)*0.5f, 0.0f);
  float margin = sqrtf(sqrtf(l2)) * 4.0f;   // sqrt(l[:,1]) * 4 * MAR, l = sqrt(eig)
  st[S_RC+s] = c;
  st[S_RS+s] = sn;
  st[S_MG+s] = margin;
}

__global__ void k_stats3(const int* __restrict__ lab, float* __restrict__ st){
  __shared__ float sh[256];
  unsigned int* ku = (unsigned int*)st;
  float mnx =  INFINITY, mxx = -INFINITY, mny =  INFINITY, mxy = -INFINITY;
  int stride = gridDim.x * blockDim.x;
  for (int p = blockIdx.x*blockDim.x + threadIdx.x; p < NPIX; p += stride){
    int s = lab[p];
    float cx = (float)(p & (WW-1)) - st[S_MUX+s];
    float cy = (float)(p >> 11)    - st[S_MUY+s];
    float c = st[S_RC+s], sn = st[S_RS+s];
    float rx =  c*cx + sn*cy;   // m^T @ coords
    float ry = -sn*cx + c*cy;
    if (s == 0){
      mnx = fminf(mnx, rx); mxx = fmaxf(mxx, rx);
      mny = fminf(mny, ry); mxy = fmaxf(mxy, ry);
    } else {
      atomicMin(&ku[S_KMINX+s], encf(rx));
      atomicMax(&ku[S_KMAXX+s], encf(rx));
      atomicMin(&ku[S_KMINY+s], encf(ry));
      atomicMax(&ku[S_KMAXY+s], encf(ry));
    }
  }
  mnx = blockReduceMin(mnx, sh);
  mxx = blockReduceMax(mxx, sh);
  mny = blockReduceMin(mny, sh);
  mxy = blockReduceMax(mxy, sh);
  if (threadIdx.x == 0){
    atomicMin(&ku[S_KMINX], encf(mnx));
    atomicMax(&ku[S_KMAXX], encf(mxx));
    atomicMin(&ku[S_KMINY], encf(mny));
    atomicMax(&ku[S_KMAXY], encf(mxy));
  }
}

__global__ void k_final(const float* __restrict__ st, const float* __restrict__ scale, float* __restrict__ out){
  int s = threadIdx.x;
  if (s >= MAXNC) return;
  const unsigned int* ku = (const unsigned int*)st;
  float a   = st[S_AREA+s];
  float lvl = st[S_SHOT+s];
  float mg  = st[S_MG+s];
  float minx = decf(ku[S_KMINX+s]) - mg;   // key init enc(0) == clamp vs 0
  float maxx = decf(ku[S_KMAXX+s]) + mg;
  float miny = decf(ku[S_KMINY+s]) - mg;
  float maxy = decf(ku[S_KMAXY+s]) + mg;
  bool ok = (lvl/a > 0.7f) && (maxx - minx > 5.0f) && (maxy - miny > 5.0f);  // NaN -> false
  float c = st[S_RC+s], sn = st[S_RS+s];
  float mux = st[S_MUX+s], muy = st[S_MUY+s];
  float sc2 = scale[0] * 2.0f;
  float rxs[5] = {minx, maxx, maxx, minx, minx};
  float rys[5] = {miny, miny, maxy, maxy, miny};
  #pragma unroll
  for (int k = 0; k < 5; ++k){
    float X = c*rxs[k] - sn*rys[k] + mux;   // m @ rec + mu
    float Y = sn*rxs[k] + c*rys[k] + muy;
    out[s*10 + 2*k + 0] = ok ? X * sc2 : 0.0f;
    out[s*10 + 2*k + 1] = ok ? Y * sc2 : 0.0f;
  }
}

// ---------------- host ----------------

extern "C" void kernel_launch(void* const* d_in, const int* in_sizes, int n_in,
                              void* d_out, int out_size, void* d_ws, size_t ws_size,
                              hipStream_t stream) {
  const float* hot   = (const float*)d_in[0];
  const float* scale = (const float*)d_in[1];
  float* out = (float*)d_out;

  char* ws = (char*)d_ws;
  size_t off = 0;
  int* lab  = (int*)(ws + off); off += (size_t)NPIX * 4;
  int* lutA = (int*)(ws + off); off += (size_t)(NPIX + 64) * 4;
  int* lutB = (int*)(ws + off); off += (size_t)(NPIX + 64) * 4;
  int* bsum = (int*)(ws + off); off += 2048 * 4;
  float* st = (float*)(ws + off); off += S_TOT * 4;

  dim3 B(256);
  int gP = (NPIX + 255) / 256;        // 16384 — pixel-range kernels
  int gL = (NPIX + 256) / 256;        // 16385 — lut-range kernels (NPIX+1 elems)

  k_init<<<gL, B, 0, stream>>>(hot, lab, lutA);

  int* cur = lutA;
  int* alt = lutB;
  const int rounds[3] = {12, 6, 3};
  for (int r = 0; r < 3; ++r){
    k_scatter<<<gP, B, 0, stream>>>(lab, cur);
    for (int i = 0; i < rounds[r]; ++i){
      k_compress<<<gL, B, 0, stream>>>(cur, alt);
      int* t = cur; cur = alt; alt = t;
    }
    k_apply<<<gP, B, 0, stream>>>(lab, cur);
  }

  // rank relabel: present -> inclusive scan -> rank
  int* pres = alt;                    // the non-current lut buffer is free now
  k_clear<<<gL, B, 0, stream>>>(pres);
  k_mark<<<gP, B, 0, stream>>>(lab, pres);
  int NB = (NPIX + 1 + 4095) / 4096;  // 1025
  k_scan1<<<NB, B, 0, stream>>>(pres, bsum);
  k_scan2<<<1, 1024, 0, stream>>>(bsum, NB);
  k_scan3<<<NB, B, 0, stream>>>(pres, bsum);
  k_seg<<<gP, B, 0, stream>>>(lab, pres);

  // per-segment stats
  k_clearstats<<<(S_TOT + 255)/256, B, 0, stream>>>(st);
  k_stats1<<<2048, B, 0, stream>>>(lab, hot, st);
  k_mu<<<1, 128, 0, stream>>>(st);
  k_stats2<<<2048, B, 0, stream>>>(lab, st);
  k_svd<<<1, 128, 0, stream>>>(st);
  k_stats3<<<2048, B, 0, stream>>>(lab, st);
  k_final<<<1, 128, 0, stream>>>(st, scale, out);
}

// Round 2
// 548.497 us; speedup vs baseline: 1.0720x; 1.0720x over previous
//
#include <hip/hip_runtime.h>
#include <math.h>

#define HH 2048
#define WW 2048
#define NPIX (HH*WW)
#define MAXNC 100

// stats layout (floats; key regions reinterpreted as uint32)
#define S_AREA 0
#define S_SX   100
#define S_SY   200
#define S_SHOT 300
#define S_MUX  400
#define S_MUY  500
#define S_CXX  600
#define S_CXY  700
#define S_CYY  800
#define S_RC   900
#define S_RS   1000
#define S_MG   1100
#define S_KMINX 1200
#define S_KMAXX 1300
#define S_KMINY 1400
#define S_KMAXY 1500
#define S_TOT  1600

__device__ __forceinline__ unsigned int encf(float f){
  unsigned int u = __float_as_uint(f);
  return (u & 0x80000000u) ? ~u : (u | 0x80000000u);
}
__device__ __forceinline__ float decf(unsigned int k){
  return (k & 0x80000000u) ? __uint_as_float(k & 0x7fffffffu) : __uint_as_float(~k);
}

__device__ __forceinline__ float blockReduceSum(float v, float* sh){
  int t = threadIdx.x;
  __syncthreads();
  sh[t] = v; __syncthreads();
  for (int o = 128; o > 0; o >>= 1){ if (t < o) sh[t] += sh[t+o]; __syncthreads(); }
  float r = sh[0]; __syncthreads();
  return r;
}
__device__ __forceinline__ float blockReduceMin(float v, float* sh){
  int t = threadIdx.x;
  __syncthreads();
  sh[t] = v; __syncthreads();
  for (int o = 128; o > 0; o >>= 1){ if (t < o) sh[t] = fminf(sh[t], sh[t+o]); __syncthreads(); }
  float r = sh[0]; __syncthreads();
  return r;
}
__device__ __forceinline__ float blockReduceMax(float v, float* sh){
  int t = threadIdx.x;
  __syncthreads();
  sh[t] = v; __syncthreads();
  for (int o = 128; o > 0; o >>= 1){ if (t < o) sh[t] = fmaxf(sh[t], sh[t+o]); __syncthreads(); }
  float r = sh[0]; __syncthreads();
  return r;
}

// ---------------- CCL ----------------

__global__ void k_init(const float* __restrict__ hot, int* __restrict__ lab, int* __restrict__ lut){
  int i = blockIdx.x*256 + threadIdx.x;
  if (i < NPIX) lab[i] = (hot[i] > 0.3f) ? (i + 1) : 0;
  if (i <= NPIX) lut[i] = i;
}

// 3x3 max via 8 clamped, fully-unrolled, INDEPENDENT loads (max is idempotent
// under duplicated border samples, and labels >= 0 so 0-pad semantics match).
__global__ void k_scatter(const int* __restrict__ lab, int* __restrict__ lut){
  int p = blockIdx.x*256 + threadIdx.x;
  if (p >= NPIX) return;
  int x = p & (WW-1);
  int y = p >> 11;
  int xm = (x > 0) ? x-1 : 0;
  int xp = (x < WW-1) ? x+1 : WW-1;
  int r0 = ((y > 0) ? y-1 : 0) << 11;
  int r1 = y << 11;
  int r2 = ((y < HH-1) ? y+1 : HH-1) << 11;
  int l  = lab[r1 + x];
  int n0 = lab[r0 + xm];
  int n1 = lab[r0 + x ];
  int n2 = lab[r0 + xp];
  int n3 = lab[r1 + xm];
  int n4 = lab[r1 + xp];
  int n5 = lab[r2 + xm];
  int n6 = lab[r2 + x ];
  int n7 = lab[r2 + xp];
  int m = max(max(max(n0,n1), max(n2,n3)), max(max(n4,n5), max(n6,n7)));
  // center == l, so window-max > l  <=>  neighbor-max > l; scattered value is the window max.
  if (l != 0 && m > l) atomicMax(&lut[l], m);
}

// Three fused synchronous pointer-doubling passes:
//   pass(x)[i] = x[x[i]];  pass^3 => dst[i] = src applied 8 times.
// 4 elements/thread (int4) for ILP on the dependent gather chains.
__global__ void k_compress8(const int* __restrict__ src, int* __restrict__ dst){
  int base = (blockIdx.x*256 + threadIdx.x) * 4;
  if (base + 3 <= NPIX){
    int4 v = *(const int4*)(src + base);
    int j0 = v.x, j1 = v.y, j2 = v.z, j3 = v.w;
    #pragma unroll
    for (int k = 0; k < 7; ++k){
      j0 = src[j0]; j1 = src[j1]; j2 = src[j2]; j3 = src[j3];
    }
    *(int4*)(dst + base) = make_int4(j0, j1, j2, j3);
  } else {
    for (int i = base; i <= NPIX; ++i){
      int j = src[i];
      #pragma unroll
      for (int k = 0; k < 7; ++k) j = src[j];
      dst[i] = j;
    }
  }
}

__global__ void k_apply(int* __restrict__ lab, const int* __restrict__ lut){
  int p = blockIdx.x*256 + threadIdx.x;
  if (p >= NPIX) return;
  lab[p] = lut[lab[p]];
}

// ---------------- rank relabel ----------------

__global__ void k_clear(int* __restrict__ pres){
  int i = blockIdx.x*256 + threadIdx.x;
  if (i <= NPIX) pres[i] = 0;
}

// round-3 apply fused with presence marking
__global__ void k_apply_mark(int* __restrict__ lab, const int* __restrict__ lut, int* __restrict__ pres){
  int p = blockIdx.x*256 + threadIdx.x;
  if (p >= NPIX) return;
  int v = lut[lab[p]];
  lab[p] = v;
  pres[v] = 1;
}

__global__ void k_scan1(const int* __restrict__ pres, int* __restrict__ bsum){
  __shared__ int sh[256];
  int t = threadIdx.x;
  int base = blockIdx.x*4096 + t*16;
  int run = 0;
  #pragma unroll
  for (int k = 0; k < 16; ++k){ int idx = base + k; if (idx <= NPIX) run += pres[idx]; }
  sh[t] = run; __syncthreads();
  for (int o = 128; o > 0; o >>= 1){ if (t < o) sh[t] += sh[t+o]; __syncthreads(); }
  if (t == 0) bsum[blockIdx.x] = sh[0];
}

__global__ void k_scan2(int* __restrict__ bs, int nb){
  __shared__ int sh[1024];
  int t = threadIdx.x;
  int v = (t < nb) ? bs[t] : 0;
  sh[t] = v; __syncthreads();
  for (int o = 1; o < 1024; o <<= 1){
    int add = (t >= o) ? sh[t-o] : 0;
    __syncthreads();
    sh[t] += add;
    __syncthreads();
  }
  if (t < nb) bs[t] = (t == 0) ? 0 : sh[t-1];   // exclusive
  if (t == 1023 && nb > 1024) bs[1024] = sh[1023]; // nb <= 1025 in this problem
}

__global__ void k_scan3(int* __restrict__ pres, const int* __restrict__ bsum){
  __shared__ int sh[256];
  int t = threadIdx.x;
  int base = blockIdx.x*4096 + t*16;
  int v[16];
  int run = 0;
  #pragma unroll
  for (int k = 0; k < 16; ++k){
    int idx = base + k;
    int x = (idx <= NPIX) ? pres[idx] : 0;
    run += x; v[k] = run;
  }
  sh[t] = run; __syncthreads();
  for (int o = 1; o < 256; o <<= 1){
    int add = (t >= o) ? sh[t-o] : 0;
    __syncthreads();
    sh[t] += add;
    __syncthreads();
  }
  int thrExcl = sh[t] - run;
  int offs = bsum[blockIdx.x] + thrExcl;
  #pragma unroll
  for (int k = 0; k < 16; ++k){
    int idx = base + k;
    if (idx <= NPIX) pres[idx] = v[k] + offs - 1;   // rank = inclusive cumsum - 1
  }
}

// ---------------- per-segment stats ----------------

__global__ void k_clearstats(float* __restrict__ st){
  int i = blockIdx.x*256 + threadIdx.x;
  if (i < S_TOT) st[i] = (i >= S_KMINX) ? -0.0f : 0.0f;  // -0.0f bits == encf(0.0f)
}

// fused: segment-id relabel (rank clamp) + first-moment accumulation
__global__ void k_stats1(int* __restrict__ lab, const int* __restrict__ ranks,
                         const float* __restrict__ hot, float* __restrict__ st){
  __shared__ float sh[256];
  float a0 = 0.f, x0 = 0.f, y0 = 0.f, h0 = 0.f;
  int stride = gridDim.x * blockDim.x;
  for (int p = blockIdx.x*blockDim.x + threadIdx.x; p < NPIX; p += stride){
    int r = ranks[lab[p]];
    int s = (r >= MAXNC) ? 0 : r;
    lab[p] = s;
    float xf = (float)(p & (WW-1));
    float yf = (float)(p >> 11);
    float hv = hot[p];
    if (s == 0){ a0 += 1.f; x0 += xf; y0 += yf; h0 += hv; }
    else {
      atomicAdd(&st[S_AREA+s], 1.f);
      atomicAdd(&st[S_SX+s], xf);
      atomicAdd(&st[S_SY+s], yf);
      atomicAdd(&st[S_SHOT+s], hv);
    }
  }
  a0 = blockReduceSum(a0, sh);
  x0 = blockReduceSum(x0, sh);
  y0 = blockReduceSum(y0, sh);
  h0 = blockReduceSum(h0, sh);
  if (threadIdx.x == 0){
    atomicAdd(&st[S_AREA], a0);
    atomicAdd(&st[S_SX], x0);
    atomicAdd(&st[S_SY], y0);
    atomicAdd(&st[S_SHOT], h0);
  }
}

__global__ void k_mu(float* __restrict__ st){
  int s = threadIdx.x;
  if (s < MAXNC){
    float a = st[S_AREA+s];
    st[S_MUX+s] = st[S_SX+s] / a;   // 0/0 -> NaN matches ref
    st[S_MUY+s] = st[S_SY+s] / a;
  }
}

__global__ void k_stats2(const int* __restrict__ lab, float* __restrict__ st){
  __shared__ float sh[256];
  float xx0 = 0.f, xy0 = 0.f, yy0 = 0.f;
  int stride = gridDim.x * blockDim.x;
  for (int p = blockIdx.x*blockDim.x + threadIdx.x; p < NPIX; p += stride){
    int s = lab[p];
    float cx = (float)(p & (WW-1)) - st[S_MUX+s];
    float cy = (float)(p >> 11)    - st[S_MUY+s];
    float pxx = cx*cx, pxy = cx*cy, pyy = cy*cy;
    if (s == 0){ xx0 += pxx; xy0 += pxy; yy0 += pyy; }
    else {
      atomicAdd(&st[S_CXX+s], pxx);
      atomicAdd(&st[S_CXY+s], pxy);
      atomicAdd(&st[S_CYY+s], pyy);
    }
  }
  xx0 = blockReduceSum(xx0, sh);
  xy0 = blockReduceSum(xy0, sh);
  yy0 = blockReduceSum(yy0, sh);
  if (threadIdx.x == 0){
    atomicAdd(&st[S_CXX], xx0);
    atomicAdd(&st[S_CXY], xy0);
    atomicAdd(&st[S_CYY], yy0);
  }
}

__global__ void k_svd(float* __restrict__ st){
  int s = threadIdx.x;
  if (s >= MAXNC) return;
  float a = st[S_AREA+s];
  float vx  = st[S_CXX+s] / a;
  float vxy = st[S_CXY+s] / a;
  float vy  = st[S_CYY+s] / a;
  float theta = 0.5f * atan2f(2.0f*vxy, vx - vy);
  float c = cosf(theta), sn = sinf(theta);
  float tr = vx + vy;
  float d = (vx - vy)*(vx - vy) + 4.0f*vxy*vxy;
  float disc = fmaxf(d, 1e-12f);
  float sq = sqrtf(disc);
  float l2 = fmaxf((tr - sq)*0.5f, 0.0f);
  float margin = sqrtf(sqrtf(l2)) * 4.0f;   // sqrt(l[:,1]) * 4 * MAR, l = sqrt(eig)
  st[S_RC+s] = c;
  st[S_RS+s] = sn;
  st[S_MG+s] = margin;
}

__global__ void k_stats3(const int* __restrict__ lab, float* __restrict__ st){
  __shared__ float sh[256];
  unsigned int* ku = (unsigned int*)st;
  float mnx =  INFINITY, mxx = -INFINITY, mny =  INFINITY, mxy = -INFINITY;
  int stride = gridDim.x * blockDim.x;
  for (int p = blockIdx.x*blockDim.x + threadIdx.x; p < NPIX; p += stride){
    int s = lab[p];
    float cx = (float)(p & (WW-1)) - st[S_MUX+s];
    float cy = (float)(p >> 11)    - st[S_MUY+s];
    float c = st[S_RC+s], sn = st[S_RS+s];
    float rx =  c*cx + sn*cy;   // m^T @ coords
    float ry = -sn*cx + c*cy;
    if (s == 0){
      mnx = fminf(mnx, rx); mxx = fmaxf(mxx, rx);
      mny = fminf(mny, ry); mxy = fmaxf(mxy, ry);
    } else {
      atomicMin(&ku[S_KMINX+s], encf(rx));
      atomicMax(&ku[S_KMAXX+s], encf(rx));
      atomicMin(&ku[S_KMINY+s], encf(ry));
      atomicMax(&ku[S_KMAXY+s], encf(ry));
    }
  }
  mnx = blockReduceMin(mnx, sh);
  mxx = blockReduceMax(mxx, sh);
  mny = blockReduceMin(mny, sh);
  mxy = blockReduceMax(mxy, sh);
  if (threadIdx.x == 0){
    atomicMin(&ku[S_KMINX], encf(mnx));
    atomicMax(&ku[S_KMAXX], encf(mxx));
    atomicMin(&ku[S_KMINY], encf(mny));
    atomicMax(&ku[S_KMAXY], encf(mxy));
  }
}

__global__ void k_final(const float* __restrict__ st, const float* __restrict__ scale, float* __restrict__ out){
  int s = threadIdx.x;
  if (s >= MAXNC) return;
  const unsigned int* ku = (const unsigned int*)st;
  float a   = st[S_AREA+s];
  float lvl = st[S_SHOT+s];
  float mg  = st[S_MG+s];
  float minx = decf(ku[S_KMINX+s]) - mg;   // key init enc(0) == clamp vs 0
  float maxx = decf(ku[S_KMAXX+s]) + mg;
  float miny = decf(ku[S_KMINY+s]) - mg;
  float maxy = decf(ku[S_KMAXY+s]) + mg;
  bool ok = (lvl/a > 0.7f) && (maxx - minx > 5.0f) && (maxy - miny > 5.0f);  // NaN -> false
  float c = st[S_RC+s], sn = st[S_RS+s];
  float mux = st[S_MUX+s], muy = st[S_MUY+s];
  float sc2 = scale[0] * 2.0f;
  float rxs[5] = {minx, maxx, maxx, minx, minx};
  float rys[5] = {miny, miny, maxy, maxy, miny};
  #pragma unroll
  for (int k = 0; k < 5; ++k){
    float X = c*rxs[k] - sn*rys[k] + mux;   // m @ rec + mu
    float Y = sn*rxs[k] + c*rys[k] + muy;
    out[s*10 + 2*k + 0] = ok ? X * sc2 : 0.0f;
    out[s*10 + 2*k + 1] = ok ? Y * sc2 : 0.0f;
  }
}

// ---------------- host ----------------

extern "C" void kernel_launch(void* const* d_in, const int* in_sizes, int n_in,
                              void* d_out, int out_size, void* d_ws, size_t ws_size,
                              hipStream_t stream) {
  const float* hot   = (const float*)d_in[0];
  const float* scale = (const float*)d_in[1];
  float* out = (float*)d_out;

  char* ws = (char*)d_ws;
  size_t off = 0;
  int* lab  = (int*)(ws + off); off += (size_t)NPIX * 4;
  int* lutA = (int*)(ws + off); off += (size_t)(NPIX + 64) * 4;
  int* lutB = (int*)(ws + off); off += (size_t)(NPIX + 64) * 4;
  int* bsum = (int*)(ws + off); off += 2048 * 4;
  float* st = (float*)(ws + off); off += S_TOT * 4;

  dim3 B(256);
  int gP = (NPIX + 255) / 256;              // 16384 — pixel-range kernels
  int gL = (NPIX + 256) / 256;              // 16385 — lut-range kernels (NPIX+1 elems)
  int gC = ((NPIX/4 + 1) + 255) / 256;      // 4097  — compress8 (4 elems/thread)

  k_init<<<gL, B, 0, stream>>>(hot, lab, lutA);

  int* cur = lutA;
  int* alt = lutB;
  const int fused[3] = {4, 2, 1};           // 12, 6, 3 passes fused 3-at-a-time
  for (int r = 0; r < 3; ++r){
    k_scatter<<<gP, B, 0, stream>>>(lab, cur);
    for (int i = 0; i < fused[r]; ++i){
      k_compress8<<<gC, B, 0, stream>>>(cur, alt);
      int* t = cur; cur = alt; alt = t;
    }
    if (r < 2) k_apply<<<gP, B, 0, stream>>>(lab, cur);
  }

  // rank relabel: round-3 apply fused with presence marking
  int* pres = alt;                    // the non-current lut buffer is free now
  k_clear<<<gL, B, 0, stream>>>(pres);
  k_apply_mark<<<gP, B, 0, stream>>>(lab, cur, pres);
  int NB = (NPIX + 1 + 4095) / 4096;  // 1025
  k_scan1<<<NB, B, 0, stream>>>(pres, bsum);
  k_scan2<<<1, 1024, 0, stream>>>(bsum, NB);
  k_scan3<<<NB, B, 0, stream>>>(pres, bsum);

  // per-segment stats (seg relabel fused into stats1)
  k_clearstats<<<(S_TOT + 255)/256, B, 0, stream>>>(st);
  k_stats1<<<2048, B, 0, stream>>>(lab, pres, hot, st);
  k_mu<<<1, 128, 0, stream>>>(st);
  k_stats2<<<2048, B, 0, stream>>>(lab, st);
  k_svd<<<1, 128, 0, stream>>>(st);
  k_stats3<<<2048, B, 0, stream>>>(lab, st);
  k_final<<<1, 128, 0, stream>>>(st, scale, out);
}

// Round 3
// 500.274 us; speedup vs baseline: 1.1753x; 1.0964x over previous
//
#include <hip/hip_runtime.h>
#include <math.h>

#define HH 2048
#define WW 2048
#define NPIX (HH*WW)
#define NP4  (NPIX/4)
#define MAXNC 100

// stats layout (floats; key regions reinterpreted as uint32)
#define S_AREA 0
#define S_SX   100
#define S_SY   200
#define S_SHOT 300
#define S_MUX  400
#define S_MUY  500
#define S_CXX  600
#define S_CXY  700
#define S_CYY  800
#define S_RC   900
#define S_RS   1000
#define S_MG   1100
#define S_KMINX 1200
#define S_KMAXX 1300
#define S_KMINY 1400
#define S_KMAXY 1500
#define S_TOT  1600

__device__ __forceinline__ unsigned int encf(float f){
  unsigned int u = __float_as_uint(f);
  return (u & 0x80000000u) ? ~u : (u | 0x80000000u);
}
__device__ __forceinline__ float decf(unsigned int k){
  return (k & 0x80000000u) ? __uint_as_float(k & 0x7fffffffu) : __uint_as_float(~k);
}

__device__ __forceinline__ float blockReduceSum(float v, float* sh){
  int t = threadIdx.x;
  __syncthreads();
  sh[t] = v; __syncthreads();
  for (int o = 128; o > 0; o >>= 1){ if (t < o) sh[t] += sh[t+o]; __syncthreads(); }
  float r = sh[0]; __syncthreads();
  return r;
}
__device__ __forceinline__ float blockReduceMin(float v, float* sh){
  int t = threadIdx.x;
  __syncthreads();
  sh[t] = v; __syncthreads();
  for (int o = 128; o > 0; o >>= 1){ if (t < o) sh[t] = fminf(sh[t], sh[t+o]); __syncthreads(); }
  float r = sh[0]; __syncthreads();
  return r;
}
__device__ __forceinline__ float blockReduceMax(float v, float* sh){
  int t = threadIdx.x;
  __syncthreads();
  sh[t] = v; __syncthreads();
  for (int o = 128; o > 0; o >>= 1){ if (t < o) sh[t] = fmaxf(sh[t], sh[t+o]); __syncthreads(); }
  float r = sh[0]; __syncthreads();
  return r;
}

// ---------------- CCL ----------------

// init labels + identity LUT + clear stats (fused)
__global__ void k_init(const float* __restrict__ hot, int* __restrict__ lab,
                       int* __restrict__ lut, float* __restrict__ st){
  int t = blockIdx.x*256 + threadIdx.x;
  if (t < NP4){
    float4 h = ((const float4*)hot)[t];
    int b = t*4;
    int4 L;
    L.x = (h.x > 0.3f) ? b+1 : 0;
    L.y = (h.y > 0.3f) ? b+2 : 0;
    L.z = (h.z > 0.3f) ? b+3 : 0;
    L.w = (h.w > 0.3f) ? b+4 : 0;
    ((int4*)lab)[t] = L;
    ((int4*)lut)[t] = make_int4(b, b+1, b+2, b+3);
  } else if (t == NP4){
    lut[NPIX] = NPIX;
  }
  if (t < S_TOT) st[t] = (t >= S_KMINX) ? -0.0f : 0.0f;  // -0.0f bits == encf(0.0f)
}

// 3x3 window max, 4 px/thread: one int4 load per row, halo via wave shuffle.
// Waves cover exactly 256 consecutive px of ONE row (512 threads/row, 8 waves/row).
// Clamped duplicate samples are idempotent under max; labels>=0 matches 0-pad.
// UNIQ: round-1 labels are unique per pixel -> plain store instead of atomicMax.
template<bool UNIQ>
__global__ void k_scatter(const int* __restrict__ lab, int* __restrict__ lut){
  int t = blockIdx.x*256 + threadIdx.x;          // 0..NP4-1
  int ci = t & 511;                              // int4 column
  int y  = t >> 9;
  int x4 = ci << 2;
  int lane = threadIdx.x & 63;
  const int4* lab4 = (const int4*)lab;
  int rm = (y > 0)    ? y-1 : 0;
  int rp = (y < HH-1) ? y+1 : HH-1;
  int4 A = lab4[(rm<<9) + ci];
  int4 B = lab4[(y <<9) + ci];
  int4 C = lab4[(rp<<9) + ci];
  int la = __shfl_up(A.w, 1), ra = __shfl_down(A.x, 1);
  int lb = __shfl_up(B.w, 1), rb = __shfl_down(B.x, 1);
  int lc = __shfl_up(C.w, 1), rc = __shfl_down(C.x, 1);
  if (lane == 0){
    if (x4 > 0){ la = lab[(rm<<11)+x4-1]; lb = lab[(y<<11)+x4-1]; lc = lab[(rp<<11)+x4-1]; }
    else       { la = A.x; lb = B.x; lc = C.x; }
  }
  if (lane == 63){
    if (x4+4 < WW){ ra = lab[(rm<<11)+x4+4]; rb = lab[(y<<11)+x4+4]; rc = lab[(rp<<11)+x4+4]; }
    else          { ra = A.w; rb = B.w; rc = C.w; }
  }
  // horizontal sliding max per row
  int ha0 = max(max(la,A.x),A.y), ha1 = max(max(A.x,A.y),A.z), ha2 = max(max(A.y,A.z),A.w), ha3 = max(max(A.z,A.w),ra);
  int hb0 = max(max(lb,B.x),B.y), hb1 = max(max(B.x,B.y),B.z), hb2 = max(max(B.y,B.z),B.w), hb3 = max(max(B.z,B.w),rb);
  int hc0 = max(max(lc,C.x),C.y), hc1 = max(max(C.x,C.y),C.z), hc2 = max(max(C.y,C.z),C.w), hc3 = max(max(C.z,C.w),rc);
  int m0 = max(ha0, max(hb0, hc0));
  int m1 = max(ha1, max(hb1, hc1));
  int m2 = max(ha2, max(hb2, hc2));
  int m3 = max(ha3, max(hb3, hc3));
  if (B.x != 0 && m0 > B.x){ if (UNIQ) lut[B.x] = m0; else atomicMax(&lut[B.x], m0); }
  if (B.y != 0 && m1 > B.y){ if (UNIQ) lut[B.y] = m1; else atomicMax(&lut[B.y], m1); }
  if (B.z != 0 && m2 > B.z){ if (UNIQ) lut[B.z] = m2; else atomicMax(&lut[B.z], m2); }
  if (B.w != 0 && m3 > B.w){ if (UNIQ) lut[B.w] = m3; else atomicMax(&lut[B.w], m3); }
}

// Three fused synchronous pointer-doubling passes: dst = src^8 (composition).
__global__ void k_compress8(const int* __restrict__ src, int* __restrict__ dst){
  int base = (blockIdx.x*256 + threadIdx.x) * 4;
  if (base + 3 <= NPIX){
    int4 v = *(const int4*)(src + base);
    int j0 = v.x, j1 = v.y, j2 = v.z, j3 = v.w;
    #pragma unroll
    for (int k = 0; k < 7; ++k){
      j0 = src[j0]; j1 = src[j1]; j2 = src[j2]; j3 = src[j3];
    }
    *(int4*)(dst + base) = make_int4(j0, j1, j2, j3);
  } else {
    for (int i = base; i <= NPIX; ++i){
      int j = src[i];
      #pragma unroll
      for (int k = 0; k < 7; ++k) j = src[j];
      dst[i] = j;
    }
  }
}

__global__ void k_apply(int* __restrict__ lab, const int* __restrict__ lut){
  int t = blockIdx.x*256 + threadIdx.x;
  if (t >= NP4) return;
  int4 L = ((int4*)lab)[t];
  L.x = lut[L.x]; L.y = lut[L.y]; L.z = lut[L.z]; L.w = lut[L.w];
  ((int4*)lab)[t] = L;
}

// ---------------- rank relabel ----------------

__global__ void k_clear(int* __restrict__ pres){
  int t = blockIdx.x*256 + threadIdx.x;
  if (t < NP4) ((int4*)pres)[t] = make_int4(0,0,0,0);
  else if (t == NP4) pres[NPIX] = 0;
}

// round-3 apply fused with presence marking
__global__ void k_apply_mark(int* __restrict__ lab, const int* __restrict__ lut, int* __restrict__ pres){
  int t = blockIdx.x*256 + threadIdx.x;
  if (t >= NP4) return;
  int4 L = ((int4*)lab)[t];
  L.x = lut[L.x]; L.y = lut[L.y]; L.z = lut[L.z]; L.w = lut[L.w];
  ((int4*)lab)[t] = L;
  pres[L.x] = 1; pres[L.y] = 1; pres[L.z] = 1; pres[L.w] = 1;
}

__global__ void k_scan1(const int* __restrict__ pres, int* __restrict__ bsum){
  __shared__ int sh[256];
  int t = threadIdx.x;
  int base = blockIdx.x*4096 + t*16;
  int run = 0;
  if (base + 15 <= NPIX){
    const int4* p4 = (const int4*)(pres + base);
    #pragma unroll
    for (int k = 0; k < 4; ++k){ int4 v = p4[k]; run += v.x + v.y + v.z + v.w; }
  } else {
    for (int k = 0; k < 16; ++k){ int idx = base + k; if (idx <= NPIX) run += pres[idx]; }
  }
  sh[t] = run; __syncthreads();
  for (int o = 128; o > 0; o >>= 1){ if (t < o) sh[t] += sh[t+o]; __syncthreads(); }
  if (t == 0) bsum[blockIdx.x] = sh[0];
}

__global__ void k_scan2(int* __restrict__ bs, int nb){
  __shared__ int sh[1024];
  int t = threadIdx.x;
  int v = (t < nb) ? bs[t] : 0;
  sh[t] = v; __syncthreads();
  for (int o = 1; o < 1024; o <<= 1){
    int add = (t >= o) ? sh[t-o] : 0;
    __syncthreads();
    sh[t] += add;
    __syncthreads();
  }
  if (t < nb) bs[t] = (t == 0) ? 0 : sh[t-1];   // exclusive
  if (t == 1023 && nb > 1024) bs[1024] = sh[1023]; // nb <= 1025 here
}

__global__ void k_scan3(int* __restrict__ pres, const int* __restrict__ bsum){
  __shared__ int sh[256];
  int t = threadIdx.x;
  int base = blockIdx.x*4096 + t*16;
  int v[16];
  int run = 0;
  bool vec = (base + 15 <= NPIX);
  if (vec){
    const int4* p4 = (const int4*)(pres + base);
    #pragma unroll
    for (int k = 0; k < 4; ++k){
      int4 q = p4[k];
      run += q.x; v[4*k]   = run;
      run += q.y; v[4*k+1] = run;
      run += q.z; v[4*k+2] = run;
      run += q.w; v[4*k+3] = run;
    }
  } else {
    #pragma unroll
    for (int k = 0; k < 16; ++k){
      int idx = base + k;
      int x = (idx <= NPIX) ? pres[idx] : 0;
      run += x; v[k] = run;
    }
  }
  sh[t] = run; __syncthreads();
  for (int o = 1; o < 256; o <<= 1){
    int add = (t >= o) ? sh[t-o] : 0;
    __syncthreads();
    sh[t] += add;
    __syncthreads();
  }
  int offs = bsum[blockIdx.x] + sh[t] - run - 1;   // rank = inclusive cumsum - 1
  if (vec){
    int4* p4 = (int4*)(pres + base);
    #pragma unroll
    for (int k = 0; k < 4; ++k)
      p4[k] = make_int4(v[4*k]+offs, v[4*k+1]+offs, v[4*k+2]+offs, v[4*k+3]+offs);
  } else {
    for (int k = 0; k < 16; ++k){ int idx = base + k; if (idx <= NPIX) pres[idx] = v[k] + offs; }
  }
}

// ---------------- per-segment stats ----------------

// fused: segment-id relabel (rank clamp) + first-moment accumulation
__global__ void k_stats1(int* __restrict__ lab, const int* __restrict__ ranks,
                         const float* __restrict__ hot, float* __restrict__ st){
  __shared__ float sh[256];
  float a0 = 0.f, x0 = 0.f, y0 = 0.f, h0 = 0.f;
  int stride = gridDim.x * blockDim.x;
  for (int t = blockIdx.x*blockDim.x + threadIdx.x; t < NP4; t += stride){
    int4 L = ((int4*)lab)[t];
    float4 hq = ((const float4*)hot)[t];
    int p0 = t*4;
    float xb = (float)(p0 & (WW-1));
    float yf = (float)(p0 >> 11);
    int ls[4] = {L.x, L.y, L.z, L.w};
    float hs[4] = {hq.x, hq.y, hq.z, hq.w};
    #pragma unroll
    for (int j = 0; j < 4; ++j){
      int r = ranks[ls[j]];
      int s = (r >= MAXNC) ? 0 : r;
      ls[j] = s;
      float xf = xb + (float)j;
      if (s == 0){ a0 += 1.f; x0 += xf; y0 += yf; h0 += hs[j]; }
      else {
        atomicAdd(&st[S_AREA+s], 1.f);
        atomicAdd(&st[S_SX+s], xf);
        atomicAdd(&st[S_SY+s], yf);
        atomicAdd(&st[S_SHOT+s], hs[j]);
      }
    }
    ((int4*)lab)[t] = make_int4(ls[0], ls[1], ls[2], ls[3]);
  }
  a0 = blockReduceSum(a0, sh);
  x0 = blockReduceSum(x0, sh);
  y0 = blockReduceSum(y0, sh);
  h0 = blockReduceSum(h0, sh);
  if (threadIdx.x == 0){
    atomicAdd(&st[S_AREA], a0);
    atomicAdd(&st[S_SX], x0);
    atomicAdd(&st[S_SY], y0);
    atomicAdd(&st[S_SHOT], h0);
  }
}

__global__ void k_mu(float* __restrict__ st){
  int s = threadIdx.x;
  if (s < MAXNC){
    float a = st[S_AREA+s];
    st[S_MUX+s] = st[S_SX+s] / a;   // 0/0 -> NaN matches ref
    st[S_MUY+s] = st[S_SY+s] / a;
  }
}

__global__ void k_stats2(const int* __restrict__ lab, float* __restrict__ st){
  __shared__ float sh[256];
  float xx0 = 0.f, xy0 = 0.f, yy0 = 0.f;
  int stride = gridDim.x * blockDim.x;
  for (int t = blockIdx.x*blockDim.x + threadIdx.x; t < NP4; t += stride){
    int4 L = ((int4*)lab)[t];
    int p0 = t*4;
    float xb = (float)(p0 & (WW-1));
    float yf = (float)(p0 >> 11);
    int ls[4] = {L.x, L.y, L.z, L.w};
    #pragma unroll
    for (int j = 0; j < 4; ++j){
      int s = ls[j];
      float cx = xb + (float)j - st[S_MUX+s];
      float cy = yf - st[S_MUY+s];
      float pxx = cx*cx, pxy = cx*cy, pyy = cy*cy;
      if (s == 0){ xx0 += pxx; xy0 += pxy; yy0 += pyy; }
      else {
        atomicAdd(&st[S_CXX+s], pxx);
        atomicAdd(&st[S_CXY+s], pxy);
        atomicAdd(&st[S_CYY+s], pyy);
      }
    }
  }
  xx0 = blockReduceSum(xx0, sh);
  xy0 = blockReduceSum(xy0, sh);
  yy0 = blockReduceSum(yy0, sh);
  if (threadIdx.x == 0){
    atomicAdd(&st[S_CXX], xx0);
    atomicAdd(&st[S_CXY], xy0);
    atomicAdd(&st[S_CYY], yy0);
  }
}

__global__ void k_svd(float* __restrict__ st){
  int s = threadIdx.x;
  if (s >= MAXNC) return;
  float a = st[S_AREA+s];
  float vx  = st[S_CXX+s] / a;
  float vxy = st[S_CXY+s] / a;
  float vy  = st[S_CYY+s] / a;
  float theta = 0.5f * atan2f(2.0f*vxy, vx - vy);
  float c = cosf(theta), sn = sinf(theta);
  float tr = vx + vy;
  float d = (vx - vy)*(vx - vy) + 4.0f*vxy*vxy;
  float disc = fmaxf(d, 1e-12f);
  float sq = sqrtf(disc);
  float l2 = fmaxf((tr - sq)*0.5f, 0.0f);
  float margin = sqrtf(sqrtf(l2)) * 4.0f;   // sqrt(l[:,1]) * 4 * MAR, l = sqrt(eig)
  st[S_RC+s] = c;
  st[S_RS+s] = sn;
  st[S_MG+s] = margin;
}

__global__ void k_stats3(const int* __restrict__ lab, float* __restrict__ st){
  __shared__ float sh[256];
  unsigned int* ku = (unsigned int*)st;
  float mnx =  INFINITY, mxx = -INFINITY, mny =  INFINITY, mxy = -INFINITY;
  int stride = gridDim.x * blockDim.x;
  for (int t = blockIdx.x*blockDim.x + threadIdx.x; t < NP4; t += stride){
    int4 L = ((int4*)lab)[t];
    int p0 = t*4;
    float xb = (float)(p0 & (WW-1));
    float yf = (float)(p0 >> 11);
    int ls[4] = {L.x, L.y, L.z, L.w};
    #pragma unroll
    for (int j = 0; j < 4; ++j){
      int s = ls[j];
      float cx = xb + (float)j - st[S_MUX+s];
      float cy = yf - st[S_MUY+s];
      float c = st[S_RC+s], sn = st[S_RS+s];
      float rx =  c*cx + sn*cy;   // m^T @ coords
      float ry = -sn*cx + c*cy;
      if (s == 0){
        mnx = fminf(mnx, rx); mxx = fmaxf(mxx, rx);
        mny = fminf(mny, ry); mxy = fmaxf(mxy, ry);
      } else {
        atomicMin(&ku[S_KMINX+s], encf(rx));
        atomicMax(&ku[S_KMAXX+s], encf(rx));
        atomicMin(&ku[S_KMINY+s], encf(ry));
        atomicMax(&ku[S_KMAXY+s], encf(ry));
      }
    }
  }
  mnx = blockReduceMin(mnx, sh);
  mxx = blockReduceMax(mxx, sh);
  mny = blockReduceMin(mny, sh);
  mxy = blockReduceMax(mxy, sh);
  if (threadIdx.x == 0){
    atomicMin(&ku[S_KMINX], encf(mnx));
    atomicMax(&ku[S_KMAXX], encf(mxx));
    atomicMin(&ku[S_KMINY], encf(mny));
    atomicMax(&ku[S_KMAXY], encf(mxy));
  }
}

__global__ void k_final(const float* __restrict__ st, const float* __restrict__ scale, float* __restrict__ out){
  int s = threadIdx.x;
  if (s >= MAXNC) return;
  const unsigned int* ku = (const unsigned int*)st;
  float a   = st[S_AREA+s];
  float lvl = st[S_SHOT+s];
  float mg  = st[S_MG+s];
  float minx = decf(ku[S_KMINX+s]) - mg;   // key init enc(0) == clamp vs 0
  float maxx = decf(ku[S_KMAXX+s]) + mg;
  float miny = decf(ku[S_KMINY+s]) - mg;
  float maxy = decf(ku[S_KMAXY+s]) + mg;
  bool ok = (lvl/a > 0.7f) && (maxx - minx > 5.0f) && (maxy - miny > 5.0f);  // NaN -> false
  float c = st[S_RC+s], sn = st[S_RS+s];
  float mux = st[S_MUX+s], muy = st[S_MUY+s];
  float sc2 = scale[0] * 2.0f;
  float rxs[5] = {minx, maxx, maxx, minx, minx};
  float rys[5] = {miny, miny, maxy, maxy, miny};
  #pragma unroll
  for (int k = 0; k < 5; ++k){
    float X = c*rxs[k] - sn*rys[k] + mux;   // m @ rec + mu
    float Y = sn*rxs[k] + c*rys[k] + muy;
    out[s*10 + 2*k + 0] = ok ? X * sc2 : 0.0f;
    out[s*10 + 2*k + 1] = ok ? Y * sc2 : 0.0f;
  }
}

// ---------------- host ----------------

extern "C" void kernel_launch(void* const* d_in, const int* in_sizes, int n_in,
                              void* d_out, int out_size, void* d_ws, size_t ws_size,
                              hipStream_t stream) {
  const float* hot   = (const float*)d_in[0];
  const float* scale = (const float*)d_in[1];
  float* out = (float*)d_out;

  char* ws = (char*)d_ws;
  size_t off = 0;
  int* lab  = (int*)(ws + off); off += (size_t)NPIX * 4;
  int* lutA = (int*)(ws + off); off += (size_t)(NPIX + 64) * 4;
  int* lutB = (int*)(ws + off); off += (size_t)(NPIX + 64) * 4;
  int* bsum = (int*)(ws + off); off += 2048 * 4;
  float* st = (float*)(ws + off); off += S_TOT * 4;

  dim3 B(256);
  int g4  = (NP4 + 255) / 256;          // 4096  — NP4-range kernels
  int g4t = (NP4 + 256) / 256;          // 4097  — NP4+1 threads (tail element)

  k_init<<<g4t, B, 0, stream>>>(hot, lab, lutA, st);

  int* cur = lutA;
  int* alt = lutB;
  const int fused[3] = {4, 2, 1};       // 12, 6, 3 ref passes, 3 fused per kernel
  for (int r = 0; r < 3; ++r){
    if (r == 0) k_scatter<true ><<<g4, B, 0, stream>>>(lab, cur);
    else        k_scatter<false><<<g4, B, 0, stream>>>(lab, cur);
    for (int i = 0; i < fused[r]; ++i){
      k_compress8<<<g4t, B, 0, stream>>>(cur, alt);
      int* t = cur; cur = alt; alt = t;
    }
    if (r < 2) k_apply<<<g4, B, 0, stream>>>(lab, cur);
  }

  // rank relabel: round-3 apply fused with presence marking
  int* pres = alt;                      // the non-current lut buffer is free now
  k_clear<<<g4t, B, 0, stream>>>(pres);
  k_apply_mark<<<g4, B, 0, stream>>>(lab, cur, pres);
  int NB = (NPIX + 1 + 4095) / 4096;    // 1025
  k_scan1<<<NB, B, 0, stream>>>(pres, bsum);
  k_scan2<<<1, 1024, 0, stream>>>(bsum, NB);
  k_scan3<<<NB, B, 0, stream>>>(pres, bsum);

  // per-segment stats (seg relabel fused into stats1; clearstats fused into init)
  k_stats1<<<2048, B, 0, stream>>>(lab, pres, hot, st);
  k_mu<<<1, 128, 0, stream>>>(st);
  k_stats2<<<2048, B, 0, stream>>>(lab, st);
  k_svd<<<1, 128, 0, stream>>>(st);
  k_stats3<<<2048, B, 0, stream>>>(lab, st);
  k_final<<<1, 128, 0, stream>>>(st, scale, out);
}